// Round 6
// baseline (81.025 us; speedup 1.0000x reference)
//
#include <hip/hip_runtime.h>
#include <math.h>

#define B    8
#define BH   4            // batches per half (two sequential halves)
#define C    1024
#define M    8
#define HW   4096
#define EPS  1e-6f
#define GAIN 0.3f

#define NT   4            // hw tiles per batch
#define NC   16           // channel chunks (CCH = 64)
#define NP   (NT*NC)      // stat partials per batch = 64 (one full wave)
#define HWT  (HW/NT)      // 1024
#define CCH  (C/NC)       // 64
#define TPB  256

typedef float floatx4 __attribute__((ext_vector_type(4)));

// workspace layout (float offsets); yz region is reused by both halves
#define OFF_YZP   0                          // [BH][NC][M][HW] = 2,097,152 floats
#define OFF_STATP (OFF_YZP + BH*NC*M*HW)     // [B][NP][2]      = 1024 floats
#define OFF_Y     (OFF_STATP + B*NP*2)       // [B][M][HW]      = 262,144 floats

// ---------------- K1: partial stats + partial yz = W @ z (per c-chunk) -----
// grid 256 = BH*NT*NC; reads this half's z (HBM-cold), leaves it in L3.
__global__ __launch_bounds__(TPB) void k1_partial(const float* __restrict__ z,
                                                  const float* __restrict__ Wd,
                                                  float* __restrict__ ws,
                                                  int b0) {
    int bid = blockIdx.x;
    int nc  = bid % NC;
    int t   = (bid / NC) % NT;
    int bl  = bid / (NC * NT);       // 0..BH-1
    int b   = b0 + bl;
    int tid = threadIdx.x;
    int hw  = t * HWT + tid * 4;
    int c0  = nc * CCH;

    float4 ym[M];
#pragma unroll
    for (int m = 0; m < M; ++m) ym[m] = make_float4(0.f, 0.f, 0.f, 0.f);
    float su = 0.f, sq = 0.f;

    const float* zp = z + ((size_t)(b * C + c0)) * HW + hw;
#pragma unroll 4
    for (int ci = 0; ci < CCH; ++ci) {
        float4 v = *reinterpret_cast<const float4*>(zp + (size_t)ci * HW);
        su += (v.x + v.y) + (v.z + v.w);
        sq += v.x * v.x + v.y * v.y + v.z * v.z + v.w * v.w;
        int c = c0 + ci;
#pragma unroll
        for (int m = 0; m < M; ++m) {
            float w = Wd[m * C + c];           // uniform -> s_load
            ym[m].x += w * v.x;
            ym[m].y += w * v.y;
            ym[m].z += w * v.z;
            ym[m].w += w * v.w;
        }
    }

    // write yz partials: [bl][nc][m][hw]
    float* yzp = ws + OFF_YZP + ((size_t)(bl * NC + nc) * M) * HW + hw;
#pragma unroll
    for (int m = 0; m < M; ++m)
        *reinterpret_cast<float4*>(yzp + (size_t)m * HW) = ym[m];

    // deterministic block tree-reduce of stats
    __shared__ float red[2 * TPB];
    red[tid] = su;
    red[TPB + tid] = sq;
    __syncthreads();
    for (int s = TPB / 2; s > 0; s >>= 1) {
        if (tid < s) {
            red[tid] += red[tid + s];
            red[TPB + tid] += red[TPB + tid + s];
        }
        __syncthreads();
    }
    if (tid == 0) {
        float* st = ws + OFF_STATP + ((size_t)b * NP + t * NC + nc) * 2;
        st[0] = red[0];
        st[1] = red[TPB];
    }
}

// ---- K2: per-(bl,m,hwblk) block — finalize stats, reduce yz -> y ----------
// grid 128: bid -> bl = bid/32, m = (bid%32)/4, hwblk = bid%4
__global__ __launch_bounds__(TPB) void k2_reduce_y(const float* __restrict__ Wd,
                                                   float* __restrict__ ws,
                                                   int b0) {
    int bid   = blockIdx.x;
    int bl    = bid >> 5;
    int m     = (bid & 31) >> 2;
    int hwblk = bid & 3;
    int b     = b0 + bl;
    int tid   = threadIdx.x;
    int wv    = tid >> 6;
    int l     = tid & 63;
    int hw    = hwblk * 1024 + tid * 4;

    __shared__ float sh[3];   // mu, istd, s_m

    if (wv == 0) {
        // stats for batch b: NP=64 partial pairs, one per lane
        const float* sp = ws + OFF_STATP + ((size_t)b * NP + l) * 2;
        float su = sp[0], sq = sp[1];
#pragma unroll
        for (int o = 32; o > 0; o >>= 1) {
            su += __shfl_down(su, o);
            sq += __shfl_down(sq, o);
        }
        if (l == 0) {
            const float invN = 1.0f / (float)(C * HW);
            float mu  = su * invN;
            float var = sq * invN - mu * mu;
            sh[0] = mu;
            sh[1] = 1.0f / sqrtf(var + EPS);
        }
    } else if (wv == 1) {
        // s[m] = sum_c W[m,c] : one wave, 16 loads/lane
        float sm = 0.f;
#pragma unroll
        for (int k = 0; k < C / 64; ++k) sm += Wd[m * C + k * 64 + l];
#pragma unroll
        for (int o = 32; o > 0; o >>= 1) sm += __shfl_down(sm, o);
        if (l == 0) sh[2] = sm;
    }
    __syncthreads();
    float mu   = sh[0];
    float istd = sh[1];
    float off  = mu * sh[2];

    // reduce yz chunk-partials for (bl, m, hw..hw+3) over all nc'
    float4 acc = make_float4(0.f, 0.f, 0.f, 0.f);
    const float* p = ws + OFF_YZP + ((size_t)bl * NC * M + m) * HW + hw;
#pragma unroll
    for (int ncp = 0; ncp < NC; ++ncp) {
        float4 v = *reinterpret_cast<const float4*>(p + (size_t)ncp * M * HW);
        acc.x += v.x; acc.y += v.y; acc.z += v.z; acc.w += v.w;
    }
    float4 y;
    y.x = istd * (acc.x - off);
    y.y = istd * (acc.y - off);
    y.z = istd * (acc.z - off);
    y.w = istd * (acc.w - off);
    *reinterpret_cast<float4*>(ws + OFF_Y + ((size_t)b * M + m) * HW + hw) = y;
}

// ---------------- K3: out = z + GAIN * W^T y -------------------------------
// z for this half should be L3-resident from K1; out stores nontemporal.
__global__ __launch_bounds__(TPB) void k3_apply(const float* __restrict__ z,
                                                const float* __restrict__ Wd,
                                                const float* __restrict__ ws,
                                                float* __restrict__ out,
                                                int b0) {
    int bid = blockIdx.x;
    int nc  = bid % NC;
    int t   = (bid / NC) % NT;
    int b   = b0 + bid / (NC * NT);
    int tid = threadIdx.x;
    int hw  = t * HWT + tid * 4;
    int c0  = nc * CCH;

    // y[m] for this thread's 4 hw positions: 32 VGPRs
    float4 y[M];
    const float* yp = ws + OFF_Y + (size_t)b * M * HW + hw;
#pragma unroll
    for (int m = 0; m < M; ++m)
        y[m] = *reinterpret_cast<const float4*>(yp + (size_t)m * HW);

    const float* zp = z + ((size_t)(b * C + c0)) * HW + hw;
    float* op = out + ((size_t)(b * C + c0)) * HW + hw;
#pragma unroll 4
    for (int ci = 0; ci < CCH; ++ci) {
        float4 v = *reinterpret_cast<const float4*>(zp + (size_t)ci * HW);
        int c = c0 + ci;
        float rx = 0.f, ry = 0.f, rz = 0.f, rw = 0.f;
#pragma unroll
        for (int m = 0; m < M; ++m) {
            float w = Wd[m * C + c];           // uniform -> s_load
            rx += w * y[m].x;
            ry += w * y[m].y;
            rz += w * y[m].z;
            rw += w * y[m].w;
        }
        floatx4 o;
        o.x = v.x + GAIN * rx;
        o.y = v.y + GAIN * ry;
        o.z = v.z + GAIN * rz;
        o.w = v.w + GAIN * rw;
        __builtin_nontemporal_store(o, reinterpret_cast<floatx4*>(op + (size_t)ci * HW));
    }
}

extern "C" void kernel_launch(void* const* d_in, const int* in_sizes, int n_in,
                              void* d_out, int out_size, void* d_ws, size_t ws_size,
                              hipStream_t stream) {
    const float* z  = (const float*)d_in[0];   // (8,1024,64,64) fp32
    const float* Wd = (const float*)d_in[1];   // (8,1024) fp32
    float* out = (float*)d_out;                // (8,1024,64,64) fp32
    float* ws  = (float*)d_ws;                 // needs ~9.5 MB

    dim3 blk(TPB);
    for (int h = 0; h < 2; ++h) {
        int b0 = h * BH;
        k1_partial<<<dim3(BH * NT * NC), blk, 0, stream>>>(z, Wd, ws, b0);
        k2_reduce_y<<<dim3(BH * M * 4), blk, 0, stream>>>(Wd, ws, b0);
        k3_apply<<<dim3(BH * NT * NC), blk, 0, stream>>>(z, Wd, ws, out, b0);
    }
}